// Round 3
// baseline (942.706 us; speedup 1.0000x reference)
//
#include <hip/hip_runtime.h>
#include <hip/hip_bf16.h>
#include <stdint.h>

#define D_DIM 256
#define KBIG 768

typedef __attribute__((ext_vector_type(8))) short bf16x8_t;
typedef __attribute__((ext_vector_type(4))) float f32x4_t;

__device__ __forceinline__ float bf2f(uint16_t u) {
    union { uint32_t i; float f; } v; v.i = ((uint32_t)u) << 16; return v.f;
}
__device__ __forceinline__ uint16_t f2bf(float f) {
    union { float f; uint32_t i; } v; v.f = f;
    uint32_t x = v.i;
    uint32_t r = (x + 0x7FFFu + ((x >> 16) & 1u)) >> 16;
    return (uint16_t)r;
}
// dual-dtype scalar load: flag=1 -> f32 source, flag=0 -> bf16 source
__device__ __forceinline__ float loadv(const void* base, int f, size_t idx) {
    return f ? ((const float*)base)[idx] : bf2f(((const uint16_t*)base)[idx]);
}

// ---- dtype detect: sample low-16 halves of u32 words of x; bf16 values have
// exponent bits (14:7) concentrated in [100,140]; f32 mantissa bits are uniform.
__global__ void k_detect(const uint32_t* __restrict__ xw, int* __restrict__ flag) {
    __shared__ int cnt[256];
    int t = threadIdx.x;
    int c = 0;
    for (int j = 0; j < 16; j++) {
        uint32_t w = xw[(size_t)(t * 16 + j) * 797];
        uint32_t e = (w >> 7) & 0xFF;
        if (e >= 100 && e <= 140) c++;
    }
    cnt[t] = c;
    __syncthreads();
    for (int off = 128; off > 0; off >>= 1) {
        if (t < off) cnt[t] += cnt[t + off];
        __syncthreads();
    }
    if (t == 0) flag[0] = (cnt[0] < 2048) ? 1 : 0;   // 1 = f32, 0 = bf16
}

// ---- transpose weights (dual dtype) into canonical bf16:
// bt_big[n][mat*256+k] = w_mat[k][n] (mat 0..2), bt_rel[n][k] = w_rel[k][n]
__global__ void k_transpose(const void* __restrict__ w0, const void* __restrict__ w1,
                            const void* __restrict__ w2, const void* __restrict__ w3,
                            const int* __restrict__ flagp,
                            uint16_t* __restrict__ bt_big, uint16_t* __restrict__ bt_rel) {
    __shared__ uint16_t tile[32][33];
    int f = *flagp;
    int mat = blockIdx.z;
    const void* src = mat == 0 ? w0 : mat == 1 ? w1 : mat == 2 ? w2 : w3;
    int k0 = blockIdx.y * 32, n0 = blockIdx.x * 32;
    int tx = threadIdx.x, ty = threadIdx.y;
    tile[ty][tx] = f2bf(loadv(src, f, (size_t)(k0 + ty) * D_DIM + n0 + tx));
    __syncthreads();
    int n = n0 + ty, k = k0 + tx;
    if (mat < 3) bt_big[(size_t)n * KBIG + mat * D_DIM + k] = tile[tx][ty];
    else         bt_rel[(size_t)n * D_DIM + k] = tile[tx][ty];
}

// ---- cvec[c] = bias[c] - (loop_rel @ w_loop)[c]
__global__ void k_cvec(const void* __restrict__ loop_rel, const void* __restrict__ w_loop,
                       const void* __restrict__ bias, const int* __restrict__ flagp,
                       float* __restrict__ cvec) {
    int f = *flagp;
    int c = threadIdx.x;
    float s = 0.f;
    for (int k = 0; k < D_DIM; k++)
        s += loadv(loop_rel, f, k) * loadv(w_loop, f, (size_t)k * D_DIM + c);
    cvec[c] = loadv(bias, f, c) - s;
}

// ---- degree histogram over row = edge_index[0]
__global__ void k_hist(const int* __restrict__ rows, int E, int* __restrict__ deg) {
    int i = blockIdx.x * blockDim.x + threadIdx.x;
    if (i < E) atomicAdd(&deg[rows[i]], 1);
}

// ---- scan stage A
__global__ void k_scan_a(const int* __restrict__ deg, int N, int* __restrict__ row_start,
                         int* __restrict__ blk_sum, float* __restrict__ dinv) {
    __shared__ int s[1024];
    int t = threadIdx.x;
    int i = blockIdx.x * 1024 + t;
    int v = (i < N) ? deg[i] : 0;
    if (i < N) dinv[i] = v > 0 ? rsqrtf((float)v) : 0.f;
    s[t] = v;
    __syncthreads();
    for (int off = 1; off < 1024; off <<= 1) {
        int add = (t >= off) ? s[t - off] : 0;
        __syncthreads();
        s[t] += add;
        __syncthreads();
    }
    if (i < N) row_start[i] = s[t] - v;
    if (t == 1023) blk_sum[blockIdx.x] = s[1023];
}

// ---- scan stage B (nb <= 128)
__global__ void k_scan_b(int* __restrict__ blk_sum, int nb) {
    __shared__ int s[128];
    int t = threadIdx.x;
    int v = (t < nb) ? blk_sum[t] : 0;
    s[t] = v;
    __syncthreads();
    for (int off = 1; off < 128; off <<= 1) {
        int add = (t >= off) ? s[t - off] : 0;
        __syncthreads();
        s[t] += add;
        __syncthreads();
    }
    if (t < nb) blk_sum[t] = s[t] - v;
}

// ---- scan stage C
__global__ void k_scan_c(int* __restrict__ row_start, const int* __restrict__ blk_sum,
                         int N, int E, int* __restrict__ cursor) {
    int i = blockIdx.x * 1024 + threadIdx.x;
    if (i < N) {
        int v = row_start[i] + blk_sum[blockIdx.x];
        row_start[i] = v;
        cursor[i] = v;
    }
    if (i == 0) row_start[N] = E;
}

// ---- fill CSR records: col | et<<17 | halfflag<<26
__global__ void k_fill(const int* __restrict__ ei, const int* __restrict__ et, int E, int half,
                       int* __restrict__ cursor, uint32_t* __restrict__ csr) {
    int e = blockIdx.x * blockDim.x + threadIdx.x;
    if (e >= E) return;
    int r_ = ei[e];
    int c_ = ei[E + e];
    int t_ = et[e];
    uint32_t rec = (uint32_t)c_ | ((uint32_t)t_ << 17) | ((e >= half) ? (1u << 26) : 0u);
    int pos = atomicAdd(&cursor[r_], 1);
    csr[pos] = rec;
}

// ---- per-node pre-matmul aggregation (dual-dtype x, r reads; bf16 outputs)
__global__ __launch_bounds__(256) void k_agg(
    const uint32_t* __restrict__ csr, const int* __restrict__ row_start,
    const float* __restrict__ dinv,
    const void* __restrict__ x, const void* __restrict__ r,
    const int* __restrict__ flagp,
    uint16_t* __restrict__ s_in, uint16_t* __restrict__ s_out, int N) {
    int f = *flagp;
    int node = blockIdx.x * 4 + (threadIdx.x >> 6);
    int lane = threadIdx.x & 63;
    if (node >= N) return;
    int s = row_start[node], e = row_start[node + 1];
    float di = dinv[node];
    int co = lane * 4;
    float ai0 = 0.f, ai1 = 0.f, ai2 = 0.f, ai3 = 0.f;
    float ao0 = 0.f, ao1 = 0.f, ao2 = 0.f, ao3 = 0.f;
    const uint16_t* xb = (const uint16_t*)x;
    const float*    xf = (const float*)x;
    const uint16_t* rb = (const uint16_t*)r;
    const float*    rf = (const float*)r;
    for (int j = s; j < e; j++) {
        uint32_t rec = csr[j];
        int c = rec & 131071;
        int et = (rec >> 17) & 511;
        int flag = (rec >> 26) & 1;
        float nrm = di * dinv[c];
        float x0, x1, x2, x3, r0, r1, r2, r3;
        if (f) {
            float4 xv = *(const float4*)(xf + (size_t)c * D_DIM + co);
            float4 rv = *(const float4*)(rf + (size_t)et * D_DIM + co);
            x0 = xv.x; x1 = xv.y; x2 = xv.z; x3 = xv.w;
            r0 = rv.x; r1 = rv.y; r2 = rv.z; r3 = rv.w;
        } else {
            ushort4 xv = *(const ushort4*)(xb + (size_t)c * D_DIM + co);
            ushort4 rv = *(const ushort4*)(rb + (size_t)et * D_DIM + co);
            x0 = bf2f(xv.x); x1 = bf2f(xv.y); x2 = bf2f(xv.z); x3 = bf2f(xv.w);
            r0 = bf2f(rv.x); r1 = bf2f(rv.y); r2 = bf2f(rv.z); r3 = bf2f(rv.w);
        }
        float v0 = (x0 - r0) * nrm, v1 = (x1 - r1) * nrm;
        float v2 = (x2 - r2) * nrm, v3 = (x3 - r3) * nrm;
        if (flag) { ao0 += v0; ao1 += v1; ao2 += v2; ao3 += v3; }
        else      { ai0 += v0; ai1 += v1; ai2 += v2; ai3 += v3; }
    }
    ushort4 oi, oo;
    oi.x = f2bf(ai0); oi.y = f2bf(ai1); oi.z = f2bf(ai2); oi.w = f2bf(ai3);
    oo.x = f2bf(ao0); oo.y = f2bf(ao1); oo.z = f2bf(ao2); oo.w = f2bf(ao3);
    *(ushort4*)(s_in  + (size_t)node * D_DIM + co) = oi;
    *(ushort4*)(s_out + (size_t)node * D_DIM + co) = oo;
}

// ---- MFMA GEMM: out[M,256] = [a0|a1|a2][M,ktot] @ bt (+ addvec)
// native_mask bit i: section i is a raw input (dtype per *flagp); else bf16.
// NOTE: out may alias a0 or a1 (per-block rows are disjoint; all reads precede epilogue).
#define BM 128
#define BK 32
#define LDT 40

__global__ __launch_bounds__(256) void k_gemm(
    const void* a0, const void* a1, const void* a2, int M,
    const uint16_t* __restrict__ bt, int bstride, int ktot,
    int native_mask, const int* __restrict__ flagp,
    const float* __restrict__ addvec, uint16_t* out) {
    __shared__ uint16_t As[BM * LDT];
    __shared__ uint16_t Bs[256 * LDT];
    int fl = *flagp;
    int t = threadIdx.x;
    int mbase = blockIdx.x * BM;
    int wave = t >> 6, lane = t & 63;
    int wm = (wave >> 1) * 64, wn = (wave & 1) * 128;
    int quad = lane >> 4, l15 = lane & 15;

    f32x4_t acc[4][8];
#pragma unroll
    for (int i = 0; i < 4; i++)
#pragma unroll
        for (int j = 0; j < 8; j++) acc[i][j] = (f32x4_t){0.f, 0.f, 0.f, 0.f};

    for (int kt = 0; kt < ktot; kt += BK) {
        const void* asec;
        int nat;
        if (kt < 256)      { asec = a0; nat = native_mask & 1; }
        else if (kt < 512) { asec = a1; nat = (native_mask >> 1) & 1; }
        else               { asec = a2; nat = (native_mask >> 2) & 1; }
        int use_f = nat & fl;
        int klocal = kt & 255;
#pragma unroll
        for (int rep = 0; rep < 2; rep++) {          // A: 128 rows x 32 k
            int idx = t + rep * 256;
            int m = idx >> 2, kk = (idx & 3) * 8;
            uint4 av = make_uint4(0u, 0u, 0u, 0u);
            int gr = mbase + m;
            if (gr < M) {
                size_t off = (size_t)gr * D_DIM + klocal + kk;
                if (use_f) {
                    const float* fp = (const float*)asec + off;
                    float4 f0 = *(const float4*)fp;
                    float4 f1 = *(const float4*)(fp + 4);
                    av.x = (uint32_t)f2bf(f0.x) | ((uint32_t)f2bf(f0.y) << 16);
                    av.y = (uint32_t)f2bf(f0.z) | ((uint32_t)f2bf(f0.w) << 16);
                    av.z = (uint32_t)f2bf(f1.x) | ((uint32_t)f2bf(f1.y) << 16);
                    av.w = (uint32_t)f2bf(f1.z) | ((uint32_t)f2bf(f1.w) << 16);
                } else {
                    av = *(const uint4*)((const uint16_t*)asec + off);
                }
            }
            *(uint4*)(&As[m * LDT + kk]) = av;
        }
#pragma unroll
        for (int rep = 0; rep < 4; rep++) {          // B: 256 rows x 32 k
            int idx = t + rep * 256;
            int n = idx >> 2, kk = (idx & 3) * 8;
            uint4 bv = *(const uint4*)(bt + (size_t)n * bstride + kt + kk);
            *(uint4*)(&Bs[n * LDT + kk]) = bv;
        }
        __syncthreads();
        bf16x8_t af[4], bfr[8];
#pragma unroll
        for (int im = 0; im < 4; im++)
            af[im] = *(const bf16x8_t*)(&As[(wm + im * 16 + l15) * LDT + quad * 8]);
#pragma unroll
        for (int in = 0; in < 8; in++)
            bfr[in] = *(const bf16x8_t*)(&Bs[(wn + in * 16 + l15) * LDT + quad * 8]);
#pragma unroll
        for (int im = 0; im < 4; im++)
#pragma unroll
            for (int in = 0; in < 8; in++)
                acc[im][in] = __builtin_amdgcn_mfma_f32_16x16x32_bf16(af[im], bfr[in], acc[im][in], 0, 0, 0);
        __syncthreads();
    }

#pragma unroll
    for (int im = 0; im < 4; im++) {
#pragma unroll
        for (int in = 0; in < 8; in++) {
            int gn = wn + in * 16 + l15;
            float av_ = addvec ? addvec[gn] : 0.f;
#pragma unroll
            for (int i = 0; i < 4; i++) {
                int gm = mbase + wm + im * 16 + quad * 4 + i;
                if (gm < M) out[(size_t)gm * D_DIM + gn] = f2bf(acc[im][in][i] + av_);
            }
        }
    }
}

// ---- BN stats
__global__ void k_stats(const uint16_t* __restrict__ h_pre, int N,
                        float* __restrict__ bn_sum, float* __restrict__ bn_sq) {
    int c = threadIdx.x;
    float s = 0.f, q = 0.f;
    for (int rw = blockIdx.x; rw < N; rw += gridDim.x) {
        float v = bf2f(h_pre[(size_t)rw * D_DIM + c]);
        s += v; q += v * v;
    }
    atomicAdd(&bn_sum[c], s);
    atomicAdd(&bn_sq[c], q);
}

// ---- BN finalize
__global__ void k_bnfin(const float* __restrict__ bn_sum, const float* __restrict__ bn_sq,
                        const void* __restrict__ gamma, const void* __restrict__ beta,
                        const int* __restrict__ flagp,
                        int N, float* __restrict__ scale, float* __restrict__ shift) {
    int f = *flagp;
    int c = threadIdx.x;
    float inv_n = 1.f / (float)N;
    float mean = bn_sum[c] * inv_n;
    float var = bn_sq[c] * inv_n - mean * mean;
    float sc = loadv(gamma, f, c) * rsqrtf(var + 1e-5f);
    scale[c] = sc;
    shift[c] = loadv(beta, f, c) - mean * sc;
}

// ---- final: normalize + tanh, write d_out h region in detected dtype
__global__ __launch_bounds__(256) void k_final(const uint16_t* __restrict__ h_pre,
                                               const float* __restrict__ scale,
                                               const float* __restrict__ shift,
                                               const int* __restrict__ flagp,
                                               void* __restrict__ dout, int total) {
    int f = *flagp;
    int t = blockIdx.x * 256 + threadIdx.x;
    int base = t * 8;
    if (base >= total) return;
    int c0 = base & (D_DIM - 1);
    uint4 v = *(const uint4*)(h_pre + base);
    uint16_t e[8];
    e[0] = (uint16_t)(v.x & 0xFFFF); e[1] = (uint16_t)(v.x >> 16);
    e[2] = (uint16_t)(v.y & 0xFFFF); e[3] = (uint16_t)(v.y >> 16);
    e[4] = (uint16_t)(v.z & 0xFFFF); e[5] = (uint16_t)(v.z >> 16);
    e[6] = (uint16_t)(v.w & 0xFFFF); e[7] = (uint16_t)(v.w >> 16);
    float r[8];
#pragma unroll
    for (int i = 0; i < 8; i++)
        r[i] = tanhf(bf2f(e[i]) * scale[c0 + i] + shift[c0 + i]);
    if (f) {
        float* fo = (float*)dout + base;
        float4 o0 = {r[0], r[1], r[2], r[3]};
        float4 o1 = {r[4], r[5], r[6], r[7]};
        *(float4*)fo = o0;
        *(float4*)(fo + 4) = o1;
    } else {
        uint4 o;
        o.x = (uint32_t)f2bf(r[0]) | ((uint32_t)f2bf(r[1]) << 16);
        o.y = (uint32_t)f2bf(r[2]) | ((uint32_t)f2bf(r[3]) << 16);
        o.z = (uint32_t)f2bf(r[4]) | ((uint32_t)f2bf(r[5]) << 16);
        o.w = (uint32_t)f2bf(r[6]) | ((uint32_t)f2bf(r[7]) << 16);
        *(uint4*)((uint16_t*)dout + base) = o;
    }
}

// ---- copy r_out stage -> d_out r region in detected dtype
__global__ void k_store_r(const uint16_t* __restrict__ stage,
                          const int* __restrict__ flagp,
                          void* __restrict__ dout, size_t off, int cnt) {
    int f = *flagp;
    int i = (blockIdx.x * 256 + threadIdx.x) * 4;
    if (i >= cnt) return;
    ushort4 v = *(const ushort4*)(stage + i);
    if (f) {
        float4 o = {bf2f(v.x), bf2f(v.y), bf2f(v.z), bf2f(v.w)};
        *(float4*)((float*)dout + off + i) = o;
    } else {
        *(ushort4*)((uint16_t*)dout + off + i) = v;
    }
}

extern "C" void kernel_launch(void* const* d_in, const int* in_sizes, int n_in,
                              void* d_out, int out_size, void* d_ws, size_t ws_size,
                              hipStream_t stream) {
    const void* x        = d_in[0];
    const void* r        = d_in[1];
    const void* w_in     = d_in[2];
    const void* w_out    = d_in[3];
    const void* w_loop   = d_in[4];
    const void* w_rel    = d_in[5];
    const void* loop_rel = d_in[6];
    const void* bias     = d_in[7];
    const void* bn_gamma = d_in[8];
    const void* bn_beta  = d_in[9];
    const int* edge_index = (const int*)d_in[10];
    const int* edge_type  = (const int*)d_in[11];

    const int N = in_sizes[0] / D_DIM;       // 100000
    const int R = in_sizes[1] / D_DIM;       // 474
    const int E = in_sizes[11];              // 1000000
    const int half = E / 2;

    // ---- workspace carve (~58 MB)
    char* p = (char*)d_ws;
    auto alloc = [&](size_t bytes) -> void* {
        void* q = (void*)p;
        p += (bytes + 255) & ~(size_t)255;
        return q;
    };
    uint16_t* s_out   = (uint16_t*)alloc((size_t)N * D_DIM * 2);   // also h_pre (in-place GEMM out)
    uint32_t* csr     = (uint32_t*)alloc((size_t)E * 4);
    uint16_t* bt_big  = (uint16_t*)alloc((size_t)D_DIM * KBIG * 2);
    uint16_t* bt_rel  = (uint16_t*)alloc((size_t)D_DIM * D_DIM * 2);
    uint16_t* r_stage = (uint16_t*)alloc((size_t)R * D_DIM * 2);
    int*      deg     = (int*)alloc((size_t)N * 4);
    int*      rstart  = (int*)alloc((size_t)(N + 1) * 4);
    int*      cursor  = (int*)alloc((size_t)N * 4);
    float*    dinv    = (float*)alloc((size_t)N * 4);
    int*      blksum  = (int*)alloc(128 * 4);
    float*    cvec    = (float*)alloc(D_DIM * 4);
    float*    bn_sum  = (float*)alloc(D_DIM * 4);
    float*    bn_sq   = (float*)alloc(D_DIM * 4);
    float*    bscale  = (float*)alloc(D_DIM * 4);
    float*    bshift  = (float*)alloc(D_DIM * 4);
    int*      dflag   = (int*)alloc(256);

    uint16_t* s_in = (uint16_t*)d_out;   // bf16 staging in d_out h region (>= 51.2MB both dtypes)
    uint16_t* h_pre = s_out;             // GEMM writes in place over s_out (a1)

    hipMemsetAsync(deg, 0, (size_t)N * 4, stream);
    hipMemsetAsync(bn_sum, 0, D_DIM * 4, stream);
    hipMemsetAsync(bn_sq, 0, D_DIM * 4, stream);

    k_detect<<<1, 256, 0, stream>>>((const uint32_t*)x, dflag);
    k_transpose<<<dim3(8, 8, 4), dim3(32, 32), 0, stream>>>(w_in, w_out, w_loop, w_rel,
                                                            dflag, bt_big, bt_rel);
    k_cvec<<<1, D_DIM, 0, stream>>>(loop_rel, w_loop, bias, dflag, cvec);

    // CSR build
    int eb = (E + 255) / 256;
    k_hist<<<eb, 256, 0, stream>>>(edge_index, E, deg);
    int nb = (N + 1023) / 1024;
    k_scan_a<<<nb, 1024, 0, stream>>>(deg, N, rstart, blksum, dinv);
    k_scan_b<<<1, 128, 0, stream>>>(blksum, nb);
    k_scan_c<<<nb, 1024, 0, stream>>>(rstart, blksum, N, E, cursor);
    k_fill<<<eb, 256, 0, stream>>>(edge_index, edge_type, E, half, cursor, csr);

    // pre-matmul aggregation: s_in -> d_out (bf16 scratch), s_out -> ws
    k_agg<<<(N + 3) / 4, 256, 0, stream>>>(csr, rstart, dinv, x, r, dflag, s_in, s_out, N);

    // h_pre = [s_in | s_out | x] @ [W_in; W_out; W_loop] + cvec  (out aliases s_out; x native)
    int gx = (N + BM - 1) / BM;
    k_gemm<<<gx, 256, 0, stream>>>(s_in, s_out, x, N, bt_big, KBIG, KBIG,
                                   /*native_mask=*/4, dflag, cvec, h_pre);
    // r_stage = r @ w_rel (r native)
    int gr_ = (R + BM - 1) / BM;
    k_gemm<<<gr_, 256, 0, stream>>>(r, r, r, R, bt_rel, D_DIM, D_DIM,
                                    /*native_mask=*/1, dflag, nullptr, r_stage);

    // BatchNorm stats + finalize + tanh -> d_out (dtype per flag)
    k_stats<<<256, D_DIM, 0, stream>>>(h_pre, N, bn_sum, bn_sq);
    k_bnfin<<<1, D_DIM, 0, stream>>>(bn_sum, bn_sq, bn_gamma, bn_beta, dflag, N, bscale, bshift);
    int total = N * D_DIM;
    k_final<<<(total / 8 + 255) / 256, 256, 0, stream>>>(h_pre, bscale, bshift, dflag, d_out, total);
    int rcnt = R * D_DIM;
    k_store_r<<<(rcnt / 4 + 255) / 256, 256, 0, stream>>>(r_stage, dflag, d_out, (size_t)N * D_DIM, rcnt);
}

// Round 4
// 788.389 us; speedup vs baseline: 1.1957x; 1.1957x over previous
//
#include <hip/hip_runtime.h>
#include <hip/hip_bf16.h>
#include <stdint.h>

#define D_DIM 256
#define KBIG 768

typedef __attribute__((ext_vector_type(8))) short bf16x8_t;
typedef __attribute__((ext_vector_type(4))) float f32x4_t;

__device__ __forceinline__ float bf2f(uint16_t u) {
    union { uint32_t i; float f; } v; v.i = ((uint32_t)u) << 16; return v.f;
}
__device__ __forceinline__ uint16_t f2bf(float f) {
    union { float f; uint32_t i; } v; v.f = f;
    uint32_t x = v.i;
    uint32_t r = (x + 0x7FFFu + ((x >> 16) & 1u)) >> 16;
    return (uint16_t)r;
}
__device__ __forceinline__ float loadv(const void* base, int f, size_t idx) {
    return f ? ((const float*)base)[idx] : bf2f(((const uint16_t*)base)[idx]);
}

// async global->LDS, 16B per lane; LDS dest = wave-uniform base + lane*16
__device__ __forceinline__ void gll16(const uint16_t* g, uint16_t* l) {
    __builtin_amdgcn_global_load_lds(
        (const __attribute__((address_space(1))) uint32_t*)(const void*)g,
        (__attribute__((address_space(3))) uint32_t*)(void*)l, 16, 0, 0);
}

// ---- dtype detect: low-16 halves of u32 words; bf16 exponents cluster in [100,140]
__global__ void k_detect(const uint32_t* __restrict__ xw, int* __restrict__ flag) {
    __shared__ int cnt[256];
    int t = threadIdx.x;
    int c = 0;
    for (int j = 0; j < 16; j++) {
        uint32_t w = xw[(size_t)(t * 16 + j) * 797];
        uint32_t e = (w >> 7) & 0xFF;
        if (e >= 100 && e <= 140) c++;
    }
    cnt[t] = c;
    __syncthreads();
    for (int off = 128; off > 0; off >>= 1) {
        if (t < off) cnt[t] += cnt[t + off];
        __syncthreads();
    }
    if (t == 0) flag[0] = (cnt[0] < 2048) ? 1 : 0;   // 1 = f32, 0 = bf16
}

// ---- cast to canonical bf16 (8 elems/thread). skip_bf: don't write when already bf16.
__global__ __launch_bounds__(256) void k_cast(const void* __restrict__ src,
                                              uint16_t* __restrict__ dst,
                                              int nvec, const int* __restrict__ flagp,
                                              int skip_bf) {
    int f = *flagp;
    int i = blockIdx.x * 256 + threadIdx.x;
    if (i >= nvec) return;
    size_t base = (size_t)i * 8;
    if (f) {
        const float* s = (const float*)src + base;
        float4 a = *(const float4*)s;
        float4 b = *(const float4*)(s + 4);
        uint4 o;
        o.x = (uint32_t)f2bf(a.x) | ((uint32_t)f2bf(a.y) << 16);
        o.y = (uint32_t)f2bf(a.z) | ((uint32_t)f2bf(a.w) << 16);
        o.z = (uint32_t)f2bf(b.x) | ((uint32_t)f2bf(b.y) << 16);
        o.w = (uint32_t)f2bf(b.z) | ((uint32_t)f2bf(b.w) << 16);
        *(uint4*)(dst + base) = o;
    } else {
        if (skip_bf) return;
        *(uint4*)(dst + base) = *(const uint4*)((const uint16_t*)src + base);
    }
}

// ---- transpose weights (dual dtype) into canonical bf16
__global__ void k_transpose(const void* __restrict__ w0, const void* __restrict__ w1,
                            const void* __restrict__ w2, const void* __restrict__ w3,
                            const int* __restrict__ flagp,
                            uint16_t* __restrict__ bt_big, uint16_t* __restrict__ bt_rel) {
    __shared__ uint16_t tile[32][33];
    int f = *flagp;
    int mat = blockIdx.z;
    const void* src = mat == 0 ? w0 : mat == 1 ? w1 : mat == 2 ? w2 : w3;
    int k0 = blockIdx.y * 32, n0 = blockIdx.x * 32;
    int tx = threadIdx.x, ty = threadIdx.y;
    tile[ty][tx] = f2bf(loadv(src, f, (size_t)(k0 + ty) * D_DIM + n0 + tx));
    __syncthreads();
    int n = n0 + ty, k = k0 + tx;
    if (mat < 3) bt_big[(size_t)n * KBIG + mat * D_DIM + k] = tile[tx][ty];
    else         bt_rel[(size_t)n * D_DIM + k] = tile[tx][ty];
}

// ---- cvec[c] = bias[c] - (loop_rel @ w_loop)[c]
__global__ void k_cvec(const void* __restrict__ loop_rel, const void* __restrict__ w_loop,
                       const void* __restrict__ bias, const int* __restrict__ flagp,
                       float* __restrict__ cvec) {
    int f = *flagp;
    int c = threadIdx.x;
    float s = 0.f;
    for (int k = 0; k < D_DIM; k++)
        s += loadv(loop_rel, f, k) * loadv(w_loop, f, (size_t)k * D_DIM + c);
    cvec[c] = loadv(bias, f, c) - s;
}

// ---- degree histogram
__global__ void k_hist(const int* __restrict__ rows, int E, int* __restrict__ deg) {
    int i = blockIdx.x * blockDim.x + threadIdx.x;
    if (i < E) atomicAdd(&deg[rows[i]], 1);
}

// ---- scan stage A
__global__ void k_scan_a(const int* __restrict__ deg, int N, int* __restrict__ row_start,
                         int* __restrict__ blk_sum, float* __restrict__ dinv) {
    __shared__ int s[1024];
    int t = threadIdx.x;
    int i = blockIdx.x * 1024 + t;
    int v = (i < N) ? deg[i] : 0;
    if (i < N) dinv[i] = v > 0 ? rsqrtf((float)v) : 0.f;
    s[t] = v;
    __syncthreads();
    for (int off = 1; off < 1024; off <<= 1) {
        int add = (t >= off) ? s[t - off] : 0;
        __syncthreads();
        s[t] += add;
        __syncthreads();
    }
    if (i < N) row_start[i] = s[t] - v;
    if (t == 1023) blk_sum[blockIdx.x] = s[1023];
}

// ---- scan stage B (nb <= 128)
__global__ void k_scan_b(int* __restrict__ blk_sum, int nb) {
    __shared__ int s[128];
    int t = threadIdx.x;
    int v = (t < nb) ? blk_sum[t] : 0;
    s[t] = v;
    __syncthreads();
    for (int off = 1; off < 128; off <<= 1) {
        int add = (t >= off) ? s[t - off] : 0;
        __syncthreads();
        s[t] += add;
        __syncthreads();
    }
    if (t < nb) blk_sum[t] = s[t] - v;
}

// ---- scan stage C
__global__ void k_scan_c(int* __restrict__ row_start, const int* __restrict__ blk_sum,
                         int N, int E, int* __restrict__ cursor) {
    int i = blockIdx.x * 1024 + threadIdx.x;
    if (i < N) {
        int v = row_start[i] + blk_sum[blockIdx.x];
        row_start[i] = v;
        cursor[i] = v;
    }
    if (i == 0) row_start[N] = E;
}

// ---- fill CSR records: col | et<<17 | halfflag<<26
__global__ void k_fill(const int* __restrict__ ei, const int* __restrict__ et, int E, int half,
                       int* __restrict__ cursor, uint32_t* __restrict__ csr) {
    int e = blockIdx.x * blockDim.x + threadIdx.x;
    if (e >= E) return;
    int r_ = ei[e];
    int c_ = ei[E + e];
    int t_ = et[e];
    uint32_t rec = (uint32_t)c_ | ((uint32_t)t_ << 17) | ((e >= half) ? (1u << 26) : 0u);
    int pos = atomicAdd(&cursor[r_], 1);
    csr[pos] = rec;
}

// ---- per-node pre-matmul aggregation (pure bf16 gathers)
__global__ __launch_bounds__(256) void k_agg(
    const uint32_t* __restrict__ csr, const int* __restrict__ row_start,
    const float* __restrict__ dinv,
    const void* __restrict__ x_raw, const uint16_t* __restrict__ x_bf,
    const uint16_t* __restrict__ r_bf, const int* __restrict__ flagp,
    uint16_t* __restrict__ s_in, uint16_t* __restrict__ s_out, int N) {
    const uint16_t* xs = (*flagp) ? x_bf : (const uint16_t*)x_raw;
    int node = blockIdx.x * 4 + (threadIdx.x >> 6);
    int lane = threadIdx.x & 63;
    if (node >= N) return;
    int s = row_start[node], e = row_start[node + 1];
    float di = dinv[node];
    int co = lane * 4;
    float ai0 = 0.f, ai1 = 0.f, ai2 = 0.f, ai3 = 0.f;
    float ao0 = 0.f, ao1 = 0.f, ao2 = 0.f, ao3 = 0.f;
    for (int j = s; j < e; j++) {
        uint32_t rec = csr[j];
        int c = rec & 131071;
        int et = (rec >> 17) & 511;
        int flag = (rec >> 26) & 1;
        float nrm = di * dinv[c];
        ushort4 xv = *(const ushort4*)(xs + (size_t)c * D_DIM + co);
        ushort4 rv = *(const ushort4*)(r_bf + (size_t)et * D_DIM + co);
        float v0 = (bf2f(xv.x) - bf2f(rv.x)) * nrm;
        float v1 = (bf2f(xv.y) - bf2f(rv.y)) * nrm;
        float v2 = (bf2f(xv.z) - bf2f(rv.z)) * nrm;
        float v3 = (bf2f(xv.w) - bf2f(rv.w)) * nrm;
        if (flag) { ao0 += v0; ao1 += v1; ao2 += v2; ao3 += v3; }
        else      { ai0 += v0; ai1 += v1; ai2 += v2; ai3 += v3; }
    }
    ushort4 oi, oo;
    oi.x = f2bf(ai0); oi.y = f2bf(ai1); oi.z = f2bf(ai2); oi.w = f2bf(ai3);
    oo.x = f2bf(ao0); oo.y = f2bf(ao1); oo.z = f2bf(ao2); oo.w = f2bf(ao3);
    *(ushort4*)(s_in  + (size_t)node * D_DIM + co) = oi;
    *(ushort4*)(s_out + (size_t)node * D_DIM + co) = oo;
}

// ---- MFMA GEMM: out[M,256] = [a0|a1|a2][M,ktot] @ bt (+ addvec)
// 512 threads = 8 waves of 64x64 tiles over a 128x256 block tile. BN=256 full
// width -> block owns all columns of its rows -> in-place out==a1 is safe.
// global_load_lds staging (16B/lane) into unpadded LDS rows of 64B with chunk
// swizzle pos = chunk ^ ((row>>1)&3) -> conflict-free ds_read_b128 frag reads.
__global__ __launch_bounds__(512) void k_gemm(
    const uint16_t* a0, const uint16_t* a1,
    const uint16_t* a2, const uint16_t* a2alt, const int* __restrict__ flagp,
    int M, const uint16_t* __restrict__ bt, int bstride, int ktot,
    const float* __restrict__ addvec, uint16_t* out) {
    __shared__ uint16_t As[128 * 32];
    __shared__ uint16_t Bs[256 * 32];
    const uint16_t* a2s = (*flagp) ? a2 : a2alt;
    int t = threadIdx.x;
    int mbase = blockIdx.x * 128;
    int wave = t >> 6, lane = t & 63;
    int wm = (wave >> 2) * 64, wn = (wave & 3) * 64;
    int quad = lane >> 4, l15 = lane & 15;

    // staging precompute (loop-invariant): 1 A-inst + 2 B-insts per wave
    int roff = lane >> 2, cidx = lane & 3;
    int arowL = wave * 16 + roff;                     // LDS row 0..127
    int achk = cidx ^ ((arowL >> 1) & 3);
    int agrow = mbase + arowL; if (agrow > M - 1) agrow = M - 1;
    size_t aoff = (size_t)agrow * D_DIM + achk * 8;
    uint16_t* aldsb = &As[(wave * 16) * 32];

    int browL0 = wave * 32 + roff;                    // LDS rows 0..255
    int browL1 = browL0 + 16;
    int bchk0 = cidx ^ ((browL0 >> 1) & 3);
    int bchk1 = cidx ^ ((browL1 >> 1) & 3);
    size_t boff0 = (size_t)browL0 * bstride + bchk0 * 8;
    size_t boff1 = (size_t)browL1 * bstride + bchk1 * 8;
    uint16_t* bldsb0 = &Bs[(wave * 32) * 32];
    uint16_t* bldsb1 = &Bs[(wave * 32 + 16) * 32];

    // fragment LDS offsets (loop-invariant, swizzled)
    int afo[4], bfo[4];
#pragma unroll
    for (int im = 0; im < 4; im++) {
        int row = wm + im * 16 + l15;
        afo[im] = row * 32 + (quad ^ ((row >> 1) & 3)) * 8;
    }
#pragma unroll
    for (int in = 0; in < 4; in++) {
        int row = wn + in * 16 + l15;
        bfo[in] = row * 32 + (quad ^ ((row >> 1) & 3)) * 8;
    }

    f32x4_t acc[4][4];
#pragma unroll
    for (int i = 0; i < 4; i++)
#pragma unroll
        for (int j = 0; j < 4; j++) acc[i][j] = (f32x4_t){0.f, 0.f, 0.f, 0.f};

    for (int kt = 0; kt < ktot; kt += 32) {
        const uint16_t* asec = (kt < 256) ? a0 : (kt < 512 ? a1 : a2s);
        int klocal = kt & 255;
        gll16(asec + aoff + klocal, aldsb);
        gll16(bt + boff0 + kt, bldsb0);
        gll16(bt + boff1 + kt, bldsb1);
        __syncthreads();
        bf16x8_t af[4], bfr[4];
#pragma unroll
        for (int im = 0; im < 4; im++) af[im] = *(const bf16x8_t*)(&As[afo[im]]);
#pragma unroll
        for (int in = 0; in < 4; in++) bfr[in] = *(const bf16x8_t*)(&Bs[bfo[in]]);
#pragma unroll
        for (int im = 0; im < 4; im++)
#pragma unroll
            for (int in = 0; in < 4; in++)
                acc[im][in] = __builtin_amdgcn_mfma_f32_16x16x32_bf16(af[im], bfr[in], acc[im][in], 0, 0, 0);
        __syncthreads();
    }

#pragma unroll
    for (int im = 0; im < 4; im++) {
#pragma unroll
        for (int in = 0; in < 4; in++) {
            int gn = wn + in * 16 + l15;
            float av_ = addvec ? addvec[gn] : 0.f;
#pragma unroll
            for (int i2 = 0; i2 < 4; i2++) {
                int gm = mbase + wm + im * 16 + quad * 4 + i2;
                if (gm < M) out[(size_t)gm * D_DIM + gn] = f2bf(acc[im][in][i2] + av_);
            }
        }
    }
}

// ---- BN stats
__global__ void k_stats(const uint16_t* __restrict__ h_pre, int N,
                        float* __restrict__ bn_sum, float* __restrict__ bn_sq) {
    int c = threadIdx.x;
    float s = 0.f, q = 0.f;
    for (int rw = blockIdx.x; rw < N; rw += gridDim.x) {
        float v = bf2f(h_pre[(size_t)rw * D_DIM + c]);
        s += v; q += v * v;
    }
    atomicAdd(&bn_sum[c], s);
    atomicAdd(&bn_sq[c], q);
}

// ---- BN finalize
__global__ void k_bnfin(const float* __restrict__ bn_sum, const float* __restrict__ bn_sq,
                        const void* __restrict__ gamma, const void* __restrict__ beta,
                        const int* __restrict__ flagp,
                        int N, float* __restrict__ scale, float* __restrict__ shift) {
    int f = *flagp;
    int c = threadIdx.x;
    float inv_n = 1.f / (float)N;
    float mean = bn_sum[c] * inv_n;
    float var = bn_sq[c] * inv_n - mean * mean;
    float sc = loadv(gamma, f, c) * rsqrtf(var + 1e-5f);
    scale[c] = sc;
    shift[c] = loadv(beta, f, c) - mean * sc;
}

// ---- final: normalize + tanh, write d_out h region in detected dtype
__global__ __launch_bounds__(256) void k_final(const uint16_t* __restrict__ h_pre,
                                               const float* __restrict__ scale,
                                               const float* __restrict__ shift,
                                               const int* __restrict__ flagp,
                                               void* __restrict__ dout, int total) {
    int f = *flagp;
    int t = blockIdx.x * 256 + threadIdx.x;
    int base = t * 8;
    if (base >= total) return;
    int c0 = base & (D_DIM - 1);
    uint4 v = *(const uint4*)(h_pre + base);
    uint16_t e[8];
    e[0] = (uint16_t)(v.x & 0xFFFF); e[1] = (uint16_t)(v.x >> 16);
    e[2] = (uint16_t)(v.y & 0xFFFF); e[3] = (uint16_t)(v.y >> 16);
    e[4] = (uint16_t)(v.z & 0xFFFF); e[5] = (uint16_t)(v.z >> 16);
    e[6] = (uint16_t)(v.w & 0xFFFF); e[7] = (uint16_t)(v.w >> 16);
    float r[8];
#pragma unroll
    for (int i = 0; i < 8; i++)
        r[i] = tanhf(bf2f(e[i]) * scale[c0 + i] + shift[c0 + i]);
    if (f) {
        float* fo = (float*)dout + base;
        float4 o0 = {r[0], r[1], r[2], r[3]};
        float4 o1 = {r[4], r[5], r[6], r[7]};
        *(float4*)fo = o0;
        *(float4*)(fo + 4) = o1;
    } else {
        uint4 o;
        o.x = (uint32_t)f2bf(r[0]) | ((uint32_t)f2bf(r[1]) << 16);
        o.y = (uint32_t)f2bf(r[2]) | ((uint32_t)f2bf(r[3]) << 16);
        o.z = (uint32_t)f2bf(r[4]) | ((uint32_t)f2bf(r[5]) << 16);
        o.w = (uint32_t)f2bf(r[6]) | ((uint32_t)f2bf(r[7]) << 16);
        *(uint4*)((uint16_t*)dout + base) = o;
    }
}

// ---- copy r_out stage -> d_out r region in detected dtype
__global__ void k_store_r(const uint16_t* __restrict__ stage,
                          const int* __restrict__ flagp,
                          void* __restrict__ dout, size_t off, int cnt) {
    int f = *flagp;
    int i = (blockIdx.x * 256 + threadIdx.x) * 4;
    if (i >= cnt) return;
    ushort4 v = *(const ushort4*)(stage + i);
    if (f) {
        float4 o = {bf2f(v.x), bf2f(v.y), bf2f(v.z), bf2f(v.w)};
        *(float4*)((float*)dout + off + i) = o;
    } else {
        *(ushort4*)((uint16_t*)dout + off + i) = v;
    }
}

extern "C" void kernel_launch(void* const* d_in, const int* in_sizes, int n_in,
                              void* d_out, int out_size, void* d_ws, size_t ws_size,
                              hipStream_t stream) {
    const void* x        = d_in[0];
    const void* r        = d_in[1];
    const void* w_in     = d_in[2];
    const void* w_out    = d_in[3];
    const void* w_loop   = d_in[4];
    const void* w_rel    = d_in[5];
    const void* loop_rel = d_in[6];
    const void* bias     = d_in[7];
    const void* bn_gamma = d_in[8];
    const void* bn_beta  = d_in[9];
    const int* edge_index = (const int*)d_in[10];
    const int* edge_type  = (const int*)d_in[11];

    const int N = in_sizes[0] / D_DIM;       // 100000
    const int R = in_sizes[1] / D_DIM;       // 474
    const int E = in_sizes[11];              // 1000000
    const int half = E / 2;

    // ---- workspace carve (~58 MB, same budget as the passing round)
    char* p = (char*)d_ws;
    auto alloc = [&](size_t bytes) -> void* {
        void* q = (void*)p;
        p += (bytes + 255) & ~(size_t)255;
        return q;
    };
    uint16_t* s_out   = (uint16_t*)alloc((size_t)N * D_DIM * 2);   // also h_pre (in-place GEMM out)
    uint32_t* csr     = (uint32_t*)alloc((size_t)E * 4);
    uint16_t* bt_big  = (uint16_t*)alloc((size_t)D_DIM * KBIG * 2);
    uint16_t* bt_rel  = (uint16_t*)alloc((size_t)D_DIM * D_DIM * 2);
    uint16_t* r_bf    = (uint16_t*)alloc((size_t)R * D_DIM * 2 + 65536); // slack for OOB-clamped rows
    uint16_t* r_stage = (uint16_t*)alloc((size_t)R * D_DIM * 2);
    int*      deg     = (int*)alloc((size_t)N * 4);
    int*      rstart  = (int*)alloc((size_t)(N + 1) * 4);
    int*      cursor  = (int*)alloc((size_t)N * 4);
    float*    dinv    = (float*)alloc((size_t)N * 4);
    int*      blksum  = (int*)alloc(128 * 4);
    float*    cvec    = (float*)alloc(D_DIM * 4);
    float*    bn_sum  = (float*)alloc(D_DIM * 4);
    float*    bn_sq   = (float*)alloc(D_DIM * 4);
    float*    bscale  = (float*)alloc(D_DIM * 4);
    float*    bshift  = (float*)alloc(D_DIM * 4);
    int*      dflag   = (int*)alloc(256);

    // s_in (bf16) lives in d_out[0 .. 51.2MB); x_bf (bf16, only when input is
    // f32) lives in d_out[51.2 .. 102.4MB) -- valid because f32 d_out h region
    // is 102.4MB. When input is bf16, x is used raw and x_bf never touched.
    uint16_t* s_in = (uint16_t*)d_out;
    uint16_t* x_bf = (uint16_t*)d_out + (size_t)N * D_DIM;
    uint16_t* h_pre = s_out;

    hipMemsetAsync(deg, 0, (size_t)N * 4, stream);
    hipMemsetAsync(bn_sum, 0, D_DIM * 4, stream);
    hipMemsetAsync(bn_sq, 0, D_DIM * 4, stream);

    k_detect<<<1, 256, 0, stream>>>((const uint32_t*)x, dflag);
    // canonical bf16 copies
    int xvec = N * D_DIM / 8;
    k_cast<<<(xvec + 255) / 256, 256, 0, stream>>>(x, x_bf, xvec, dflag, /*skip_bf=*/1);
    int rvec = R * D_DIM / 8;
    k_cast<<<(rvec + 255) / 256, 256, 0, stream>>>(r, r_bf, rvec, dflag, /*skip_bf=*/0);
    k_transpose<<<dim3(8, 8, 4), dim3(32, 32), 0, stream>>>(w_in, w_out, w_loop, w_rel,
                                                            dflag, bt_big, bt_rel);
    k_cvec<<<1, D_DIM, 0, stream>>>(loop_rel, w_loop, bias, dflag, cvec);

    // CSR build
    int eb = (E + 255) / 256;
    k_hist<<<eb, 256, 0, stream>>>(edge_index, E, deg);
    int nb = (N + 1023) / 1024;
    k_scan_a<<<nb, 1024, 0, stream>>>(deg, N, rstart, blksum, dinv);
    k_scan_b<<<1, 128, 0, stream>>>(blksum, nb);
    k_scan_c<<<nb, 1024, 0, stream>>>(rstart, blksum, N, E, cursor);
    k_fill<<<eb, 256, 0, stream>>>(edge_index, edge_type, E, half, cursor, csr);

    // pre-matmul aggregation: s_in -> d_out, s_out -> ws
    k_agg<<<(N + 3) / 4, 256, 0, stream>>>(csr, rstart, dinv, x, x_bf, r_bf, dflag,
                                           s_in, s_out, N);

    // h_pre = [s_in | s_out | x] @ [W_in; W_out; W_loop] + cvec (in place over s_out)
    int gx = (N + 127) / 128;
    k_gemm<<<gx, 512, 0, stream>>>(s_in, s_out, x_bf, (const uint16_t*)x, dflag,
                                   N, bt_big, KBIG, KBIG, cvec, h_pre);
    // r_stage = r @ w_rel
    int gr_ = (R + 127) / 128;
    k_gemm<<<gr_, 512, 0, stream>>>(r_bf, r_bf, r_bf, r_bf, dflag,
                                    R, bt_rel, D_DIM, D_DIM, nullptr, r_stage);

    // BatchNorm stats + finalize + tanh -> d_out (dtype per flag)
    k_stats<<<256, D_DIM, 0, stream>>>(h_pre, N, bn_sum, bn_sq);
    k_bnfin<<<1, D_DIM, 0, stream>>>(bn_sum, bn_sq, bn_gamma, bn_beta, dflag, N, bscale, bshift);
    int total = N * D_DIM;
    k_final<<<(total / 8 + 255) / 256, 256, 0, stream>>>(h_pre, bscale, bshift, dflag, d_out, total);
    int rcnt = R * D_DIM;
    k_store_r<<<(rcnt / 4 + 255) / 256, 256, 0, stream>>>(r_stage, dflag, d_out, (size_t)N * D_DIM, rcnt);
}